// Round 5
// baseline (4799.249 us; speedup 1.0000x reference)
//
#include <hip/hip_runtime.h>

#define SEQ   1024
#define DIN   64
#define NHID  256
#define NBLK  64
#define NTHR  512

typedef _Float16 f16x8 __attribute__((ext_vector_type(8)));
typedef float    f32x4 __attribute__((ext_vector_type(4)));
typedef unsigned int u32x4 __attribute__((ext_vector_type(4)));
typedef unsigned long long u64;

#define MFMA16(a,b,c) __builtin_amdgcn_mfma_f32_16x16x32_f16((a),(b),(c),0,0,0)
#define ALOAD(p)   __hip_atomic_load((p), __ATOMIC_RELAXED, __HIP_MEMORY_SCOPE_AGENT)
#define ASTORE(p,v) __hip_atomic_store((p), (v), __ATOMIC_RELAXED, __HIP_MEMORY_SCOPE_AGENT)

__device__ __forceinline__ float sigm(float v){
  return __builtin_amdgcn_rcpf(1.f + __expf(-v));
}
__device__ __forceinline__ float tanh_f(float v){
  return 1.f - 2.f*__builtin_amdgcn_rcpf(__expf(2.f*v)+1.f);
}

__device__ __forceinline__ f16x8 cvt8(f32x4 a, f32x4 b){
  f16x8 r;
  r[0]=(_Float16)a[0]; r[1]=(_Float16)a[1]; r[2]=(_Float16)a[2]; r[3]=(_Float16)a[3];
  r[4]=(_Float16)b[0]; r[5]=(_Float16)b[1]; r[6]=(_Float16)b[2]; r[7]=(_Float16)b[3];
  return r;
}

union U32H2 { unsigned int u; _Float16 h[2]; unsigned short us[2]; };

// 64 blocks = 16 groups (16 batch rows) x 4 members (64 hidden cols).
// Zero-barrier, zero-LDS recurrence. All h state lives in tagged u64 words
// {hi = tag, lo = f16 colpair} in L3 (agent-scope relaxed atomics).
// State t occupies parity t&1 with tag t+1 (so memset-0 / 0xAA poison never
// match a polled tag, which runs 1..SEQ+1). Every wave reads EVERY word of
// its group's 4 slices each step -> publish(s+1) only after seeing all 32
// group waves' state-s words, whose publishes follow their complete reads of
// state s-1 => overwrite-safe, max skew 1, no barriers or fences anywhere.
__global__ void __launch_bounds__(NTHR, 1)
lstm_seq(const float* __restrict__ x, const float* __restrict__ h0,
         const float* __restrict__ c0, const float* __restrict__ Wi,
         const float* __restrict__ bi, const float* __restrict__ Wh,
         const float* __restrict__ bh, const float* __restrict__ Wcls,
         const float* __restrict__ bcls,
         u64* __restrict__ slices, float* __restrict__ out)
{
  const int bid = blockIdx.x;
  const int grp = bid & 15;          // batch group (16 rows)
  const int q   = bid >> 4;          // hidden quarter 0..3
  const int tid = threadIdx.x;
  const int w   = tid >> 6;          // wave 0..7
  const int l   = tid & 63;
  const int l15 = l & 15;
  const int lhi = l >> 4;

  // ---- A-frags: weights, register-resident f16, permuted rows ----
  // m-tile mt = w*2+t ; A-row mr=l15 ; jl = (mt>>1)*8 + ((mr>>2)<<1) + (mt&1)
  // original weight row = (mr&3)*256 + q*64 + jl  (gate = mr&3)
  f16x8 wa[2][8], xa[2][2];
#pragma unroll
  for (int t=0;t<2;t++){
    const int mt  = w*2 + t;
    const int mr  = l15;
    const int jl  = (mt>>1)*8 + ((mr>>2)<<1) + (mt&1);
    const int row = (mr&3)*NHID + q*64 + jl;
#pragma unroll
    for (int kt=0;kt<8;kt++){
      const float* p = Wh + row*NHID + kt*32 + lhi*8;
      wa[t][kt] = cvt8(*(const f32x4*)p, *(const f32x4*)(p+4));
    }
#pragma unroll
    for (int kt=0;kt<2;kt++){
      const float* p = Wi + row*DIN + kt*32 + lhi*8;
      xa[t][kt] = cvt8(*(const f32x4*)p, *(const f32x4*)(p+4));
    }
  }

  // per-lane bias (acc init) and cell state; lane owns jl = w*8 + lhi*2 + t
  f32x4 binit0, binit1; float c[2];
#pragma unroll
  for (int t=0;t<2;t++){
    const int jl = w*8 + lhi*2 + t;
    f32x4 bv;
#pragma unroll
    for (int g=0; g<4; g++)
      bv[g] = bi[g*NHID + q*64 + jl] + bh[g*NHID + q*64 + jl];
    if (t==0) binit0 = bv; else binit1 = bv;
    c[t] = c0[(size_t)(grp*16+l15)*NHID + q*64 + jl];
  }

  u64* gb0 = slices + (size_t)grp*4*512;                       // parity 0 group base
  u64* gb1 = slices + (size_t)NBLK*512 + (size_t)grp*4*512;    // parity 1 group base

  // publish state 0 (own quarter of h0): thread tid -> word tid, tag 1
  {
    const int jp = tid >> 4, b = tid & 15;      // colpair-in-quarter, batch
    const int col = q*64 + jp*2;
    U32H2 pk0;
    pk0.h[0] = (_Float16)h0[(size_t)(grp*16+b)*NHID + col];
    pk0.h[1] = (_Float16)h0[(size_t)(grp*16+b)*NHID + col+1];
    ASTORE(gb0 + q*512 + tid, ((u64)1u << 32) | (u64)pk0.u);
  }

  // x(0) -> acc preinit (bias folded), prefetch x(1)
  const float* xrow = x + (size_t)(grp*16 + l15) * (SEQ*DIN);
  f32x4 xp0,xp1,xp2,xp3;
  {
    const float* p = xrow + lhi*8;
    xp0 = *(const f32x4*)p;      xp1 = *(const f32x4*)(p+4);
    xp2 = *(const f32x4*)(p+32); xp3 = *(const f32x4*)(p+36);
  }
  f32x4 acc0, acc1;
  {
    f16x8 xb0 = cvt8(xp0, xp1), xb1 = cvt8(xp2, xp3);
    acc0 = MFMA16(xa[0][0], xb0, binit0);
    acc0 = MFMA16(xa[0][1], xb1, acc0);
    acc1 = MFMA16(xa[1][0], xb0, binit1);
    acc1 = MFMA16(xa[1][1], xb1, acc1);
  }
  {
    const float* p = xrow + DIN + lhi*8;
    xp0 = *(const f32x4*)p;      xp1 = *(const f32x4*)(p+4);
    xp2 = *(const f32x4*)(p+32); xp3 = *(const f32x4*)(p+36);
  }

  for (int s=0; s<SEQ; s++){
    u64* par = (s&1) ? gb1 : gb0;
    u64* nxt = (s&1) ? gb0 : gb1;
    const unsigned tag = (unsigned)(s+1);

    // issue ALL 32 tagged-word loads (4 quarters x 8) so L3 trips overlap
    u64 v[4][8];
#pragma unroll
    for (int qq=0; qq<4; qq++)
#pragma unroll
      for (int h2=0; h2<2; h2++)
#pragma unroll
        for (int j=0; j<4; j++)
          v[qq][h2*4+j] = ALOAD(par + qq*512 + (h2*16 + lhi*4 + j)*16 + l15);
    __builtin_amdgcn_sched_barrier(0);   // pin: all 32 issued before any poll

    f32x4 a0 = acc0, a1 = acc1;
    f32x4 b0 = {0.f,0.f,0.f,0.f}, b1 = {0.f,0.f,0.f,0.f};
#pragma unroll
    for (int qq=0; qq<4; qq++){
      // poll this quarter until all 8 tags match
      for (;;){
        bool ok = true;
#pragma unroll
        for (int j=0;j<8;j++) ok &= ((unsigned)(v[qq][j] >> 32) == tag);
        if (ok) break;
#pragma unroll
        for (int j=0;j<8;j++)
          v[qq][j] = ALOAD(par + qq*512 + ((j>>2)*16 + lhi*4 + (j&3))*16 + l15);
      }
      // B-frags from payload dwords (colpairs are consecutive cols)
      u32x4 t0, t1;
#pragma unroll
      for (int j=0;j<4;j++){ t0[j] = (unsigned)v[qq][j]; t1[j] = (unsigned)v[qq][4+j]; }
      const f16x8 f0 = __builtin_bit_cast(f16x8, t0);
      const f16x8 f1 = __builtin_bit_cast(f16x8, t1);
      a0 = MFMA16(wa[0][2*qq  ], f0, a0);
      b0 = MFMA16(wa[0][2*qq+1], f1, b0);
      a1 = MFMA16(wa[1][2*qq  ], f0, a1);
      b1 = MFMA16(wa[1][2*qq+1], f1, b1);
    }
    const f32x4 g0 = a0 + b0, g1 = a1 + b1;

    // ---- pointwise in-register (r: 0=f,1=i,2=g,3=o) ----
    U32H2 pk;
    {
      const float f0 = sigm (g0[0]);
      const float i0 = sigm (g0[1]);
      const float gg0= tanh_f(g0[2]);
      const float o0 = sigm (g0[3]);
      c[0] = c[0]*f0 + i0*gg0;
      pk.h[0] = (_Float16)(tanh_f(c[0])*o0);
      const float f1 = sigm (g1[0]);
      const float i1 = sigm (g1[1]);
      const float gg1= tanh_f(g1[2]);
      const float o1 = sigm (g1[3]);
      c[1] = c[1]*f1 + i1*gg1;
      pk.h[1] = (_Float16)(tanh_f(c[1])*o1);
    }
    // publish state s+1 immediately (tag s+2), coalesced: word = w*64+l
    ASTORE(nxt + q*512 + w*64 + l, ((u64)(unsigned)(s+2) << 32) | (u64)pk.u);

    // next-step input projection + x prefetch (overlaps partners' polls)
    {
      f16x8 xb0 = cvt8(xp0, xp1), xb1 = cvt8(xp2, xp3);
      acc0 = MFMA16(xa[0][0], xb0, binit0);
      acc0 = MFMA16(xa[0][1], xb1, acc0);
      acc1 = MFMA16(xa[1][0], xb0, binit1);
      acc1 = MFMA16(xa[1][1], xb1, acc1);
    }
    {
      const int sn = (s < SEQ-2) ? s+2 : SEQ-1;
      const float* p = xrow + sn*DIN + lhi*8;
      xp0 = *(const f32x4*)p;      xp1 = *(const f32x4*)(p+4);
      xp2 = *(const f32x4*)(p+32); xp3 = *(const f32x4*)(p+36);
    }
  }

  // classifier: q==0 blocks read final state SEQ (parity 0, tag SEQ+1)
  if (q == 0 && tid < 160){
    const int b = tid/10, j = tid - b*10;
    float sum = bcls[j];
    for (int cp=0; cp<128; cp++){
      const int qq = cp >> 5, jp = cp & 31;
      const u64* p = gb0 + qq*512 + jp*16 + b;
      u64 vv = ALOAD(p);
      while ((unsigned)(vv >> 32) != (unsigned)(SEQ+1)) vv = ALOAD(p);
      U32H2 u; u.u = (unsigned)vv;
      sum += Wcls[j*NHID + cp*2]     * (float)u.h[0]
           + Wcls[j*NHID + cp*2 + 1] * (float)u.h[1];
    }
    out[(grp*16+b)*10 + j] = sum;
  }
}

extern "C" void kernel_launch(void* const* d_in, const int* in_sizes, int n_in,
                              void* d_out, int out_size, void* d_ws, size_t ws_size,
                              hipStream_t stream){
  const float* x    = (const float*)d_in[0];
  const float* h0   = (const float*)d_in[1];
  const float* c0   = (const float*)d_in[2];
  const float* Wi   = (const float*)d_in[3];
  const float* bi   = (const float*)d_in[4];
  const float* Wh   = (const float*)d_in[5];
  const float* bh   = (const float*)d_in[6];
  const float* Wcls = (const float*)d_in[7];
  const float* bcls = (const float*)d_in[8];

  u64* slices = (u64*)d_ws;   // 2 parities x 64 slices x 512 u64 = 524288 B

  // zero all tags every launch: polled tags are 1..SEQ+1, so 0 never matches
  hipMemsetAsync(slices, 0, 2*NBLK*512*sizeof(u64), stream);
  hipLaunchKernelGGL(lstm_seq, dim3(NBLK), dim3(NTHR), 0, stream,
                     x, h0, c0, Wi, bi, Wh, bh, Wcls, bcls,
                     slices, (float*)d_out);
}

// Round 6
// 2309.338 us; speedup vs baseline: 2.0782x; 2.0782x over previous
//
#include <hip/hip_runtime.h>

#define SEQ   1024
#define DIN   64
#define NHID  256
#define NBLK  32
#define NTHR  512

typedef _Float16 f16x8 __attribute__((ext_vector_type(8)));
typedef float    f32x4 __attribute__((ext_vector_type(4)));
typedef unsigned long long u64;

#define MFMA16(a,b,c) __builtin_amdgcn_mfma_f32_16x16x32_f16((a),(b),(c),0,0,0)
#define ALOAD(p)    __hip_atomic_load((p), __ATOMIC_RELAXED, __HIP_MEMORY_SCOPE_AGENT)
#define ASTORE(p,v) __hip_atomic_store((p),(v), __ATOMIC_RELAXED, __HIP_MEMORY_SCOPE_AGENT)

__device__ __forceinline__ float sigm(float v){
  return __builtin_amdgcn_rcpf(1.f + __expf(-v));
}
__device__ __forceinline__ float tanh_f(float v){
  return 1.f - 2.f*__builtin_amdgcn_rcpf(__expf(2.f*v)+1.f);
}

__device__ __forceinline__ f16x8 cvt8(f32x4 a, f32x4 b){
  f16x8 r;
  r[0]=(_Float16)a[0]; r[1]=(_Float16)a[1]; r[2]=(_Float16)a[2]; r[3]=(_Float16)a[3];
  r[4]=(_Float16)b[0]; r[5]=(_Float16)b[1]; r[6]=(_Float16)b[2]; r[7]=(_Float16)b[3];
  return r;
}

union U32H2 { unsigned int u; _Float16 h[2]; unsigned short us[2]; };

// 32 blocks = 16 groups (16 batch rows) x 2 halves (128 hidden cols = 512 gate
// rows). Pair {g, g+16}: same blockIdx%8 -> same XCD. Fan-in 1.
// Transposed MFMA D = W'.h^T, row permutation: m-tile mt (0..31), A-row mr:
// gate = mr&3, jl = (mt>>1)*8 + ((mr>>2)<<1) + (mt&1). Wave w owns mt=w*4+t;
// lane (l15,lhi) owns gates f,i,g,o of cols jl(t) = (mt>>1)*8+lhi*2+(mt&1) for
// batch l15 -> two adjacent col-pairs cp0=8w+lhi, cp1=8w+4+lhi -> two coalesced
// tagged u64 publishes. Poller: word i of partner slice = (cp=i>>4, b=i&15);
// lane polls words tid and 512+tid (full 1024-word coverage per block).
__global__ void __launch_bounds__(NTHR, 2)
lstm_seq(const float* __restrict__ x, const float* __restrict__ h0,
         const float* __restrict__ c0, const float* __restrict__ Wi,
         const float* __restrict__ bi, const float* __restrict__ Wh,
         const float* __restrict__ bh, const float* __restrict__ Wcls,
         const float* __restrict__ bcls,
         u64* __restrict__ slices, float* __restrict__ out)
{
  __shared__ __align__(16) unsigned int hbuf[2][16*128]; // 16 KB, word ^= (b&7)<<2
  __shared__ __align__(16) float bini[NTHR*16];          // 32 KB per-lane bias

  const int bid = blockIdx.x;
  const int grp = bid & 15;          // batch group (16 rows)
  const int half= bid >> 4;          // hidden half 0..1
  const int tid = threadIdx.x;
  const int w   = tid >> 6;          // wave 0..7
  const int l   = tid & 63;
  const int l15 = l & 15;
  const int lhi = l >> 4;

  // ---- weights register-resident: 4 m-tiles per wave ----
  f16x8 wa[4][8], xa[4][2];
#pragma unroll
  for (int t=0;t<4;t++){
    const int mt  = w*4 + t;
    const int jlA = (mt>>1)*8 + ((l15>>2)<<1) + (mt&1);
    const int row = (l15&3)*NHID + half*128 + jlA;   // gate*256 + global col
#pragma unroll
    for (int kt=0;kt<8;kt++){
      const float* p = Wh + row*NHID + kt*32 + lhi*8;
      wa[t][kt] = cvt8(*(const f32x4*)p, *(const f32x4*)(p+4));
    }
#pragma unroll
    for (int kt=0;kt<2;kt++){
      const float* p = Wi + row*DIN + kt*32 + lhi*8;
      xa[t][kt] = cvt8(*(const f32x4*)p, *(const f32x4*)(p+4));
    }
  }

  // per-lane bias -> LDS (read back in poll shadow); cell state in VGPRs
  float c[4];
#pragma unroll
  for (int t=0;t<4;t++){
    const int mt = w*4 + t;
    const int jl = (mt>>1)*8 + lhi*2 + (mt&1);
    const int col= half*128 + jl;
    f32x4 bv;
#pragma unroll
    for (int g=0;g<4;g++) bv[g] = bi[g*NHID + col] + bh[g*NHID + col];
    *(f32x4*)(bini + tid*16 + t*4) = bv;
    c[t] = c0[(size_t)(grp*16+l15)*NHID + col];
  }

  // h0 -> hbuf[0] (full 256 cols, both halves load it from global)
  for (int i=tid; i<16*128; i+=NTHR){
    const int b = i>>7, cp = i&127;
    U32H2 pk;
    pk.h[0] = (_Float16)h0[(size_t)(grp*16+b)*NHID + cp*2];
    pk.h[1] = (_Float16)h0[(size_t)(grp*16+b)*NHID + cp*2 + 1];
    hbuf[0][i ^ ((b&7)<<2)] = pk.u;
  }
  __syncthreads();

  // x(0) -> acc init (bias from own bini region: lane-private), prefetch x(1)
  const float* xrow = x + (size_t)(grp*16 + l15) * (SEQ*DIN);
  f32x4 xp0,xp1,xp2,xp3;
  {
    const float* p = xrow + lhi*8;
    xp0 = *(const f32x4*)p;      xp1 = *(const f32x4*)(p+4);
    xp2 = *(const f32x4*)(p+32); xp3 = *(const f32x4*)(p+36);
  }
  f32x4 acc[4];
  {
    f16x8 xb0 = cvt8(xp0,xp1), xb1 = cvt8(xp2,xp3);
#pragma unroll
    for (int t=0;t<4;t++){
      acc[t] = MFMA16(xa[t][0], xb0, *(const f32x4*)(bini + tid*16 + t*4));
      acc[t] = MFMA16(xa[t][1], xb1, acc[t]);
    }
  }
  {
    const float* p = xrow + DIN + lhi*8;
    xp0 = *(const f32x4*)p;      xp1 = *(const f32x4*)(p+4);
    xp2 = *(const f32x4*)(p+32); xp3 = *(const f32x4*)(p+36);
  }

  u64* own0 = slices + (size_t)(grp*2 + half)*1024;
  u64* par0 = slices + (size_t)(grp*2 + (half^1))*1024;

  for (int s=0; s<SEQ; s++){
    const unsigned int* hr = hbuf[s&1];
    unsigned int*       hw_= hbuf[(s+1)&1];
    u64* ownp = own0 + (size_t)(s&1)*NBLK*1024;
    u64* parp = par0 + (size_t)(s&1)*NBLK*1024;
    const unsigned tag = (unsigned)(s+1);

    // recurrent MFMAs: B-frags from swizzled hbuf, 4 independent acc chains
#pragma unroll
    for (int kt=0;kt<8;kt++){
      const int word = (l15*128 + kt*16 + lhi*4) ^ ((l15&7)<<2);
      const f16x8 hb = *(const f16x8*)(hr + word);
#pragma unroll
      for (int t=0;t<4;t++) acc[t] = MFMA16(wa[t][kt], hb, acc[t]);
    }

    // pointwise in-register (r: 0=f,1=i,2=g,3=o)
    U32H2 pk0, pk1;
    {
      float hv[4];
#pragma unroll
      for (int t=0;t<4;t++){
        const float f = sigm (acc[t][0]);
        const float i = sigm (acc[t][1]);
        const float g = tanh_f(acc[t][2]);
        const float o = sigm (acc[t][3]);
        c[t] = c[t]*f + i*g;
        hv[t] = tanh_f(c[t])*o;
      }
      pk0.h[0]=(_Float16)hv[0]; pk0.h[1]=(_Float16)hv[1];
      pk1.h[0]=(_Float16)hv[2]; pk1.h[1]=(_Float16)hv[3];
    }
    // publish own two col-pairs: words w*128+l and w*128+64+l (coalesced)
    ASTORE(ownp + w*128      + l, ((u64)tag<<32) | (u64)pk0.u);
    ASTORE(ownp + w*128 + 64 + l, ((u64)tag<<32) | (u64)pk1.u);
    // own half -> hbuf (cp0 = 8w+lhi, cp1 = 8w+4+lhi)
    hw_[(l15*128 + half*64 + 8*w   + lhi) ^ ((l15&7)<<2)] = pk0.u;
    hw_[(l15*128 + half*64 + 8*w+4 + lhi) ^ ((l15&7)<<2)] = pk1.u;

    // issue both partner polls, then fill the latency shadow with next-step
    // x-projection + x prefetch, then check/retry
    const u64* pp0 = parp + tid;
    const u64* pp1 = parp + 512 + tid;
    u64 v0 = ALOAD(pp0);
    u64 v1 = ALOAD(pp1);
    {
      f16x8 xb0 = cvt8(xp0,xp1), xb1 = cvt8(xp2,xp3);
#pragma unroll
      for (int t=0;t<4;t++){
        acc[t] = MFMA16(xa[t][0], xb0, *(const f32x4*)(bini + tid*16 + t*4));
        acc[t] = MFMA16(xa[t][1], xb1, acc[t]);
      }
    }
    {
      const int sn = (s < SEQ-2) ? s+2 : SEQ-1;
      const float* p = xrow + sn*DIN + lhi*8;
      xp0 = *(const f32x4*)p;      xp1 = *(const f32x4*)(p+4);
      xp2 = *(const f32x4*)(p+32); xp3 = *(const f32x4*)(p+36);
    }
    while (((unsigned)(v0>>32) != tag) || ((unsigned)(v1>>32) != tag)){
      v0 = ALOAD(pp0);
      v1 = ALOAD(pp1);
    }
    // partner half -> hbuf: word tid -> cp=tid>>4 (b = tid&15 = l15)
    {
      const int ph  = (half^1)*64;
      const int cpw = tid >> 4;                 // 0..31
      hw_[(l15*128 + ph + cpw)      ^ ((l15&7)<<2)] = (unsigned)v0;
      hw_[(l15*128 + ph + 32 + cpw) ^ ((l15&7)<<2)] = (unsigned)v1;
    }
    __syncthreads();   // h(s+1) complete in hw_; also WAR guard for hbuf
  }

  // classifier: half==0 blocks hold full final h in hbuf[SEQ&1] = hbuf[0]
  if (half == 0 && tid < 160){
    const int b = tid/10, j = tid - b*10;
    const unsigned int* hf = hbuf[SEQ&1];
    float sum = bcls[j];
    for (int cp=0; cp<128; cp++){
      U32H2 v; v.u = hf[(b*128 + cp) ^ ((b&7)<<2)];
      sum += Wcls[j*NHID + cp*2]     * (float)v.h[0]
           + Wcls[j*NHID + cp*2 + 1] * (float)v.h[1];
    }
    out[(grp*16+b)*10 + j] = sum;
  }
}

extern "C" void kernel_launch(void* const* d_in, const int* in_sizes, int n_in,
                              void* d_out, int out_size, void* d_ws, size_t ws_size,
                              hipStream_t stream){
  const float* x    = (const float*)d_in[0];
  const float* h0   = (const float*)d_in[1];
  const float* c0   = (const float*)d_in[2];
  const float* Wi   = (const float*)d_in[3];
  const float* bi   = (const float*)d_in[4];
  const float* Wh   = (const float*)d_in[5];
  const float* bh   = (const float*)d_in[6];
  const float* Wcls = (const float*)d_in[7];
  const float* bcls = (const float*)d_in[8];

  u64* slices = (u64*)d_ws;   // 2 parities x 32 slices x 1024 u64 = 524288 B

  // zero all tags every launch: polled tags are 1..SEQ, 0 never matches
  hipMemsetAsync(slices, 0, (size_t)2*NBLK*1024*sizeof(u64), stream);
  hipLaunchKernelGGL(lstm_seq, dim3(NBLK), dim3(NTHR), 0, stream,
                     x, h0, c0, Wi, bi, Wh, bh, Wcls, bcls,
                     slices, (float*)d_out);
}